// Round 5
// baseline (209.540 us; speedup 1.0000x reference)
//
#include <hip/hip_runtime.h>
#include <hip/hip_bf16.h>

// Reduction of the reference (h0 = 0):
//   z  = sigmoid(x @ Wz + bz),  t = tanh(x @ Wh + bh),  h = (1-z)*t
//   out= sigmoid(relu(h @ fc1) @ fc2)       (w_r/b_r, edge_index dead)
// Main cost: [100000,256] @ [256,64] -> bf16 MFMA.
//
// R4 post-mortem: stage->barrier->MFMA->barrier at VGPR_Count=52 was
// latency-bound (VALU 12%, HBM 10%, MFMA 1.8%). R5: drop LDS staging
// entirely. The 32x32x16 A-fragment (lane holds A[m=lane&31][k=(lane>>5)*8+j],
// verified by R4 passing) is read DIRECTLY from x: lanes i and i+32 cover one
// aligned 64 B row segment. Each wave owns 32 nodes; no __syncthreads in the
// main loop; 16 fully-unrolled k-steps -> ~32 independent dwordx4 loads in
// flight. B-frags from 32 KB L2-hot pre-swizzled Wf. LDS only for the
// epilogue h-exchange (wave-private).

#define NF    256
#define TILE  32            // nodes per wave
#define WPB   4             // waves per block
#define MB    (TILE * WPB)  // 128 nodes per block
#define NTHR  256
#define HSTR  36            // Hs row stride (floats): 144 B, 16B-aligned rows

typedef __attribute__((ext_vector_type(8)))  short  short8;
typedef __attribute__((ext_vector_type(16))) float  floatx16;

__device__ __forceinline__ unsigned f2bf(float f) {
    __hip_bfloat16 h = __float2bfloat16(f);   // RNE
    return (unsigned)*(unsigned short*)&h;
}
__device__ __forceinline__ float fast_sigmoid(float v) {
    return 1.0f / (1.0f + __expf(-v));
}
__device__ __forceinline__ float fast_tanh(float v) {
    return 1.0f - 2.0f / (1.0f + __expf(2.0f * v));
}

// ---- prep: fold w[0]+w[1], emit bf16 in 32x32x16 B-fragment order:
// Wf[((kt*2+nt)*64 + lane)*8 + j] = W[kt*16 + (lane>>5)*8 + j][nt*32 + (lane&31)]
__global__ void prep_W(const float* __restrict__ wz,   // (2, 288, 32)
                       const float* __restrict__ wh,   // (2, 288, 32)
                       unsigned short* __restrict__ Wf) // 16*2*64*8 bf16
{
    int idx = blockIdx.x * blockDim.x + threadIdx.x;   // 0 .. 16383
    if (idx >= NF * 64) return;
    int j    = idx & 7;
    int lane = (idx >> 3) & 63;
    int nt   = (idx >> 9) & 1;
    int kt   = idx >> 10;                  // 0..15
    int k = kt * 16 + (lane >> 5) * 8 + j; // 0..255
    int o = nt * 32 + (lane & 31);         // 0..63
    const int PLANE = 288 * 32;
    float v;
    if (o < 32) v = wz[k * 32 + o]        + wz[PLANE + k * 32 + o];
    else        v = wh[k * 32 + (o - 32)] + wh[PLANE + k * 32 + (o - 32)];
    Wf[idx] = (unsigned short)f2bf(v);
}

__global__ void __launch_bounds__(NTHR, 3)
rgcn_main(const float* __restrict__ x,     // [N, 256]
          const unsigned short* __restrict__ Wf, // B-frags (ws)
          const float* __restrict__ bz,    // [32]
          const float* __restrict__ bh,    // [32]
          const float* __restrict__ fc1w,  // [32][32] (in,out)
          const float* __restrict__ fc1b,  // [32]
          const float* __restrict__ fc2w,  // [32]
          const float* __restrict__ fc2b,  // [1]
          float* __restrict__ out,         // [N]
          int n_nodes)
{
    __shared__ float Hs[WPB * TILE * HSTR];   // 18432 B, epilogue only

    const int tid   = threadIdx.x;
    const int lane  = tid & 63;
    const int wave  = tid >> 6;              // 0..3
    const int node0 = blockIdx.x * MB + wave * TILE;

    // A-fragment source: row = own node (clamped), cols koff..koff+7
    const int m    = lane & 31;
    const int koff = (lane >> 5) * 8;
    int gn_a = node0 + m;
    if (gn_a >= n_nodes) gn_a = n_nodes - 1;  // clamp: value unused, no fault
    const float* xr = x + (size_t)gn_a * NF + koff;

    floatx16 acc0 = {};                       // z cols (nt=0)
    floatx16 acc1 = {};                       // h cols (nt=1)

#pragma unroll
    for (int kt = 0; kt < 16; ++kt) {
        // A: 8 consecutive fp32 of this node's row (lanes i,i+32 -> 64 B seg)
        float4 v0 = *(const float4*)(xr + kt * 16);
        float4 v1 = *(const float4*)(xr + kt * 16 + 4);
        // B: pre-swizzled fragments, 32 KB total -> L2-hot
        const uint4* bp = (const uint4*)Wf + (size_t)(kt * 2) * 64 + lane;
        uint4 b0u = bp[0];
        uint4 b1u = bp[64];
        union { short8 s; unsigned u[4]; } a, b0, b1;
        a.u[0] = f2bf(v0.x) | (f2bf(v0.y) << 16);
        a.u[1] = f2bf(v0.z) | (f2bf(v0.w) << 16);
        a.u[2] = f2bf(v1.x) | (f2bf(v1.y) << 16);
        a.u[3] = f2bf(v1.z) | (f2bf(v1.w) << 16);
        b0.u[0] = b0u.x; b0.u[1] = b0u.y; b0.u[2] = b0u.z; b0.u[3] = b0u.w;
        b1.u[0] = b1u.x; b1.u[1] = b1u.y; b1.u[2] = b1u.z; b1.u[3] = b1u.w;
        acc0 = __builtin_amdgcn_mfma_f32_32x32x16_bf16(a.s, b0.s, acc0, 0, 0, 0);
        acc1 = __builtin_amdgcn_mfma_f32_32x32x16_bf16(a.s, b1.s, acc1, 0, 0, 0);
    }

    // ---- epilogue: gates in-register (C/D: col=lane&31,
    // row=(reg&3)+8*(reg>>2)+4*(lane>>5)), h -> wave-private LDS, fc head.
    const int nc = lane & 31;
    const float bzn = bz[nc];
    const float bhn = bh[nc];
    float* Hw = Hs + wave * TILE * HSTR;
#pragma unroll
    for (int r = 0; r < 16; ++r) {
        int row = (r & 3) + 8 * (r >> 2) + 4 * (lane >> 5);
        float z = fast_sigmoid(acc0[r] + bzn);
        float t = fast_tanh   (acc1[r] + bhn);
        Hw[row * HSTR + nc] = (1.0f - z) * t;
    }
    __syncthreads();   // orders LDS write->read (all 256 threads reach this)

    // fc head: 2 lanes per node, each does 16 of fc1's 32 outputs
    const int nl   = lane & 31;
    const int half = lane >> 5;
    const float* hp = Hw + nl * HSTR;
    float h[32];
#pragma unroll
    for (int q = 0; q < 8; ++q) {
        float4 v = *(const float4*)(hp + q * 4);
        h[q * 4 + 0] = v.x; h[q * 4 + 1] = v.y;
        h[q * 4 + 2] = v.z; h[q * 4 + 3] = v.w;
    }
    float part = 0.0f;
    for (int jj = 0; jj < 16; ++jj) {
        int j = (half << 4) + jj;          // 2 addrs/wave -> L1 broadcast
        float s = fc1b[j];
#pragma unroll
        for (int o = 0; o < 32; ++o)
            s = fmaf(h[o], fc1w[o * 32 + j], s);
        part = fmaf(fmaxf(s, 0.0f), fc2w[j], part);
    }
    part += __shfl_xor(part, 32);          // combine the two j-halves
    if (half == 0) {
        int gn = node0 + nl;
        if (gn < n_nodes)
            out[gn] = fast_sigmoid(part + fc2b[0]);   // 32-lane coalesced
    }
}

extern "C" void kernel_launch(void* const* d_in, const int* in_sizes, int n_in,
                              void* d_out, int out_size, void* d_ws, size_t ws_size,
                              hipStream_t stream) {
    // 0:x 1:edge_index(dead) 2:w_z 3:b_z 4:w_r(dead) 5:b_r(dead)
    // 6:w_h 7:b_h 8:fc1_w 9:fc1_b 10:fc2_w 11:fc2_b
    const float* x    = (const float*)d_in[0];
    const float* wz   = (const float*)d_in[2];
    const float* bz   = (const float*)d_in[3];
    const float* wh   = (const float*)d_in[6];
    const float* bh   = (const float*)d_in[7];
    const float* fc1w = (const float*)d_in[8];
    const float* fc1b = (const float*)d_in[9];
    const float* fc2w = (const float*)d_in[10];
    const float* fc2b = (const float*)d_in[11];
    float* out = (float*)d_out;
    unsigned short* Wf = (unsigned short*)d_ws;   // 32 KB of B-fragments

    const int n = in_sizes[0] / NF;   // 100000

    prep_W<<<(NF * 64 + 255) / 256, 256, 0, stream>>>(wz, wh, Wf);
    rgcn_main<<<(n + MB - 1) / MB, NTHR, 0, stream>>>(
        x, Wf, bz, bh, fc1w, fc1b, fc2w, fc2b, out, n);
}

// Round 6
// 205.285 us; speedup vs baseline: 1.0207x; 1.0207x over previous
//
#include <hip/hip_runtime.h>
#include <hip/hip_bf16.h>

// Reduction of the reference (h0 = 0):
//   z  = sigmoid(x @ Wz + bz),  t = tanh(x @ Wh + bh),  h = (1-z)*t
//   out= sigmoid(relu(h @ fc1) @ fc2)       (w_r/b_r, edge_index dead)
// Main cost: [100000,256] @ [256,64] -> bf16 MFMA, memory-bound on x.
//
// R5 post-mortem: VGPR-mediated loads (VGPR_Count=40) -> ~1-2 loads in
// flight/wave -> 1.5 TB/s effective, latency-bound. R6: stage x via
// __builtin_amdgcn_global_load_lds width=16 (no dest regs; wave issues its
// full 8 KB staging quota back-to-back). 4 chunks x 32 KB fp32/block;
// +16 B pad per 1 KB instruction-group (stride 1040 B) so the 64-lane
// ds_read_b128 A-frag read spreads uniformly over banks. B-frags stay
// direct L2-hot loads from pre-swizzled Wf. 33.3 KB LDS -> 4 blocks/CU.

#define NF     256
#define TILE   32            // nodes per wave
#define WPB    4             // waves per block
#define MB     (TILE * WPB)  // 128 nodes per block
#define NTHR   256
#define GRP    1040          // bytes per 1 KB instruction-group (+16 pad)
#define HSTR   36            // epilogue Hs row stride (floats)

typedef __attribute__((ext_vector_type(8)))  short  short8;
typedef __attribute__((ext_vector_type(16))) float  floatx16;
typedef __attribute__((address_space(1))) const unsigned int gu32;
typedef __attribute__((address_space(3))) unsigned int       lu32;

__device__ __forceinline__ unsigned f2bf(float f) {
    __hip_bfloat16 h = __float2bfloat16(f);   // RNE
    return (unsigned)*(unsigned short*)&h;
}
__device__ __forceinline__ float fast_sigmoid(float v) {
    return 1.0f / (1.0f + __expf(-v));
}
__device__ __forceinline__ float fast_tanh(float v) {
    return 1.0f - 2.0f / (1.0f + __expf(2.0f * v));
}

// ---- prep: fold w[0]+w[1], emit bf16 in 32x32x16 B-fragment order:
// Wf[((kt*2+nt)*64 + lane)*8 + j] = W[kt*16 + (lane>>5)*8 + j][nt*32 + (lane&31)]
__global__ void prep_W(const float* __restrict__ wz,   // (2, 288, 32)
                       const float* __restrict__ wh,   // (2, 288, 32)
                       unsigned short* __restrict__ Wf) // 16*2*64*8 bf16
{
    int idx = blockIdx.x * blockDim.x + threadIdx.x;   // 0 .. 16383
    if (idx >= NF * 64) return;
    int j    = idx & 7;
    int lane = (idx >> 3) & 63;
    int nt   = (idx >> 9) & 1;
    int kt   = idx >> 10;                  // 0..15
    int k = kt * 16 + (lane >> 5) * 8 + j; // 0..255
    int o = nt * 32 + (lane & 31);         // 0..63
    const int PLANE = 288 * 32;
    float v;
    if (o < 32) v = wz[k * 32 + o]        + wz[PLANE + k * 32 + o];
    else        v = wh[k * 32 + (o - 32)] + wh[PLANE + k * 32 + (o - 32)];
    Wf[idx] = (unsigned short)f2bf(v);
}

__global__ void __launch_bounds__(NTHR, 4)
rgcn_main(const float* __restrict__ x,     // [N, 256]
          const unsigned short* __restrict__ Wf, // B-frags (ws)
          const float* __restrict__ bz,    // [32]
          const float* __restrict__ bh,    // [32]
          const float* __restrict__ fc1w,  // [32][32] (in,out)
          const float* __restrict__ fc1b,  // [32]
          const float* __restrict__ fc2w,  // [32]
          const float* __restrict__ fc2b,  // [1]
          float* __restrict__ out,         // [N]
          int n_nodes)
{
    __shared__ __align__(16) char S[32 * GRP];   // 33280 B

    const int tid   = threadIdx.x;
    const int lane  = tid & 63;
    const int wave  = tid >> 6;              // 0..3
    const int node0 = blockIdx.x * MB;
    const int wb    = wave * TILE;           // wave's local node base

    // staging lane roles (fixed across chunks)
    const int rsel = lane >> 4;              // row within instruction 0..3
    const int cb   = (lane & 15) * 16;       // byte within 256 B row-chunk

    // A-frag read address pieces
    const int m    = wb + (lane & 31);       // local node this lane computes
    const int koff = (lane >> 5) * 8;        // k sub-offset (floats)
    const char* arow = S + (m >> 2) * GRP + (m & 3) * 256;

    floatx16 acc0 = {};                      // z cols (nt=0)
    floatx16 acc1 = {};                      // h cols (nt=1)

#pragma unroll
    for (int c = 0; c < 4; ++c) {
        if (c) __syncthreads();              // buffer readers done
        // ---- stage chunk c: 128 rows x 256 B, 8 instructions per wave.
        // LDS dest = wave-uniform base + lane*16 (HW rule); group stride
        // GRP=1040 B de-aliases banks for the b128 consumer reads.
#pragma unroll
        for (int i = 0; i < 8; ++i) {
            int inst = wave * 8 + i;
            int row  = node0 + inst * 4 + rsel;
            if (row >= n_nodes) row = n_nodes - 1;   // clamped: finite junk
            const char* g = (const char*)x + (size_t)row * (NF * 4)
                          + c * 256 + cb;
            char* lp = S + inst * GRP;               // wave-uniform
            __builtin_amdgcn_global_load_lds((gu32*)g, (lu32*)lp, 16, 0, 0);
        }
        __syncthreads();                     // drains vmcnt -> data visible

        // ---- 4 k-steps of 32x32x16 MFMA on this chunk
#pragma unroll
        for (int kt = 0; kt < 4; ++kt) {
            int ktg = c * 4 + kt;
            const float4* ap = (const float4*)(arow + (kt * 16 + koff) * 4);
            float4 v0 = ap[0];
            float4 v1 = ap[1];
            const uint4* bp = (const uint4*)Wf + (size_t)(ktg * 2) * 64 + lane;
            uint4 b0u = bp[0];
            uint4 b1u = bp[64];
            union { short8 s; unsigned u[4]; } a, b0, b1;
            a.u[0] = f2bf(v0.x) | (f2bf(v0.y) << 16);
            a.u[1] = f2bf(v0.z) | (f2bf(v0.w) << 16);
            a.u[2] = f2bf(v1.x) | (f2bf(v1.y) << 16);
            a.u[3] = f2bf(v1.z) | (f2bf(v1.w) << 16);
            b0.u[0] = b0u.x; b0.u[1] = b0u.y; b0.u[2] = b0u.z; b0.u[3] = b0u.w;
            b1.u[0] = b1u.x; b1.u[1] = b1u.y; b1.u[2] = b1u.z; b1.u[3] = b1u.w;
            acc0 = __builtin_amdgcn_mfma_f32_32x32x16_bf16(a.s, b0.s, acc0, 0, 0, 0);
            acc1 = __builtin_amdgcn_mfma_f32_32x32x16_bf16(a.s, b1.s, acc1, 0, 0, 0);
        }
    }

    // ---- epilogue: gates in-register (C/D: col=lane&31,
    // row=(reg&3)+8*(reg>>2)+4*(lane>>5)), h -> wave-private LDS, fc head.
    __syncthreads();                         // staging buffer dead from here
    float* Hs = (float*)S;
    float* Hw = Hs + wave * TILE * HSTR;
    const int nc = lane & 31;
    const float bzn = bz[nc];
    const float bhn = bh[nc];
#pragma unroll
    for (int r = 0; r < 16; ++r) {
        int row = (r & 3) + 8 * (r >> 2) + 4 * (lane >> 5);
        float z = fast_sigmoid(acc0[r] + bzn);
        float t = fast_tanh   (acc1[r] + bhn);
        Hw[row * HSTR + nc] = (1.0f - z) * t;
    }
    __syncthreads();

    // fc head: 2 lanes per node, each does 16 of fc1's 32 outputs
    const int nl   = lane & 31;
    const int half = lane >> 5;
    const float* hp = Hw + nl * HSTR;
    float h[32];
#pragma unroll
    for (int q = 0; q < 8; ++q) {
        float4 v = *(const float4*)(hp + q * 4);
        h[q * 4 + 0] = v.x; h[q * 4 + 1] = v.y;
        h[q * 4 + 2] = v.z; h[q * 4 + 3] = v.w;
    }
    float part = 0.0f;
    for (int jj = 0; jj < 16; ++jj) {
        int j = (half << 4) + jj;            // 2 addrs/wave -> L1 broadcast
        float s = fc1b[j];
#pragma unroll
        for (int o = 0; o < 32; ++o)
            s = fmaf(h[o], fc1w[o * 32 + j], s);
        part = fmaf(fmaxf(s, 0.0f), fc2w[j], part);
    }
    part += __shfl_xor(part, 32);            // combine the two j-halves
    if (half == 0) {
        int gn = node0 + wb + nl;
        if (gn < n_nodes)
            out[gn] = fast_sigmoid(part + fc2b[0]);   // 32-lane coalesced
    }
}

extern "C" void kernel_launch(void* const* d_in, const int* in_sizes, int n_in,
                              void* d_out, int out_size, void* d_ws, size_t ws_size,
                              hipStream_t stream) {
    // 0:x 1:edge_index(dead) 2:w_z 3:b_z 4:w_r(dead) 5:b_r(dead)
    // 6:w_h 7:b_h 8:fc1_w 9:fc1_b 10:fc2_w 11:fc2_b
    const float* x    = (const float*)d_in[0];
    const float* wz   = (const float*)d_in[2];
    const float* bz   = (const float*)d_in[3];
    const float* wh   = (const float*)d_in[6];
    const float* bh   = (const float*)d_in[7];
    const float* fc1w = (const float*)d_in[8];
    const float* fc1b = (const float*)d_in[9];
    const float* fc2w = (const float*)d_in[10];
    const float* fc2b = (const float*)d_in[11];
    float* out = (float*)d_out;
    unsigned short* Wf = (unsigned short*)d_ws;   // 32 KB of B-fragments

    const int n = in_sizes[0] / NF;   // 100000

    prep_W<<<(NF * 64 + 255) / 256, 256, 0, stream>>>(wz, wh, Wf);
    rgcn_main<<<(n + MB - 1) / MB, NTHR, 0, stream>>>(
        x, Wf, bz, bh, fc1w, fc1b, fc2w, fc2b, out, n);
}

// Round 7
// 203.390 us; speedup vs baseline: 1.0302x; 1.0093x over previous
//
#include <hip/hip_runtime.h>
#include <hip/hip_bf16.h>

// Reduction of the reference (h0 = 0):
//   z  = sigmoid(x @ Wz + bz),  t = tanh(x @ Wh + bh),  h = (1-z)*t
//   out= sigmoid(relu(h @ fc1) @ fc2)       (w_r/b_r, edge_index dead)
// Main cost: [100000,256] @ [256,64] -> bf16 MFMA, memory-bound on x
// (102.4 MB fp32 read; floor ~16.3 us at 6.3 TB/s).
//
// R4/R5/R6 post-mortem: all ~63-67 us with <12% on every pipe. Common
// cause: ~zero average outstanding bytes (R5: compiler recycled load regs,
// VGPR=40 -> ~2 loads in flight; R4/R6: per-chunk __syncthreads forces
// vmcnt(0) lockstep drain across all waves). R7: per-wave register
// double-buffer of A (float4 x8 ping-pong, issue chunk c+1 BEFORE compute
// of chunk c, pinned with sched_barrier(0)) -> ~8 KB/wave in flight
// continuously, x12 waves/CU ~ 96 KB/CU. B staged to LDS once per block
// (padded groups; lane-stride-16 b128 reads = structural-minimum LDS
// phases). Zero barriers in the K-loop.

#define NF    256
#define TILE  32            // nodes per wave
#define WPB   4             // waves per block
#define MB    (TILE * WPB)  // 128 nodes per block
#define NTHR  256
#define BGRP  1040          // bytes per B fragment-group (1024 + 16 pad)
#define HSTR  36            // epilogue Hs row stride (floats)

typedef __attribute__((ext_vector_type(8)))  short  short8;
typedef __attribute__((ext_vector_type(16))) float  floatx16;

__device__ __forceinline__ unsigned f2bf(float f) {
    __hip_bfloat16 h = __float2bfloat16(f);   // RNE
    return (unsigned)*(unsigned short*)&h;
}
__device__ __forceinline__ float fast_sigmoid(float v) {
    return 1.0f / (1.0f + __expf(-v));
}
__device__ __forceinline__ float fast_tanh(float v) {
    return 1.0f - 2.0f / (1.0f + __expf(2.0f * v));
}

// ---- prep: fold w[0]+w[1], emit bf16 in 32x32x16 B-fragment order:
// Wf[((kt*2+nt)*64 + lane)*8 + j] = W[kt*16 + (lane>>5)*8 + j][nt*32 + (lane&31)]
__global__ void prep_W(const float* __restrict__ wz,   // (2, 288, 32)
                       const float* __restrict__ wh,   // (2, 288, 32)
                       unsigned short* __restrict__ Wf) // 16*2*64*8 bf16
{
    int idx = blockIdx.x * blockDim.x + threadIdx.x;   // 0 .. 16383
    if (idx >= NF * 64) return;
    int j    = idx & 7;
    int lane = (idx >> 3) & 63;
    int nt   = (idx >> 9) & 1;
    int kt   = idx >> 10;                  // 0..15
    int k = kt * 16 + (lane >> 5) * 8 + j; // 0..255
    int o = nt * 32 + (lane & 31);         // 0..63
    const int PLANE = 288 * 32;
    float v;
    if (o < 32) v = wz[k * 32 + o]        + wz[PLANE + k * 32 + o];
    else        v = wh[k * 32 + (o - 32)] + wh[PLANE + k * 32 + (o - 32)];
    Wf[idx] = (unsigned short)f2bf(v);
}

__global__ void __launch_bounds__(NTHR, 3)
rgcn_main(const float* __restrict__ x,     // [N, 256]
          const unsigned short* __restrict__ Wf, // B-frags (ws)
          const float* __restrict__ bz,    // [32]
          const float* __restrict__ bh,    // [32]
          const float* __restrict__ fc1w,  // [32][32] (in,out)
          const float* __restrict__ fc1b,  // [32]
          const float* __restrict__ fc2w,  // [32]
          const float* __restrict__ fc2b,  // [1]
          float* __restrict__ out,         // [N]
          int n_nodes)
{
    __shared__ __align__(16) char SB[32 * BGRP];        // 33280 B: B frags
    __shared__ float Hs[WPB * TILE * HSTR];             // 18432 B: epilogue

    const int tid   = threadIdx.x;
    const int lane  = tid & 63;
    const int wave  = tid >> 6;              // 0..3
    const int node0 = blockIdx.x * MB;

    // ---- stage B fragments into LDS once (32 KB, L2-hot source).
    // group g = kt*2+nt at byte g*BGRP; within group: lane*16.
    {
        const uint4* src = (const uint4*)Wf;             // 2048 uint4
#pragma unroll
        for (int i = 0; i < 8; ++i) {
            int q = i * NTHR + tid;                      // coalesced
            uint4 v = src[q];
            *(uint4*)(SB + (q >> 6) * BGRP + (q & 63) * 16) = v;
        }
    }
    __syncthreads();   // the only block-wide barrier

    // ---- A source: lane's own node row (clamped), 8 floats per kt
    const int m  = lane & 31;
    int gn_a = node0 + wave * TILE + m;
    if (gn_a >= n_nodes) gn_a = n_nodes - 1;   // junk but finite
    const float* xr = x + (size_t)gn_a * NF + (lane >> 5) * 8;

    floatx16 acc0 = {};                      // z cols (nt=0)
    floatx16 acc1 = {};                      // h cols (nt=1)

    float4 bufA[8], bufB[8];
    const char* bl = SB + lane * 16;

    // issue chunk 0 (4 kt = 8 float4 per lane)
#pragma unroll
    for (int t = 0; t < 8; ++t)
        bufA[t] = *(const float4*)(xr + (t >> 1) * 16 + (t & 1) * 4);
    __builtin_amdgcn_sched_barrier(0);

#pragma unroll
    for (int c = 0; c < 4; ++c) {
        // prefetch chunk c+1 into the other buffer, pinned above compute
        if (c < 3) {
            float4* nb = ((c & 1) == 0) ? bufB : bufA;
            const float* xc = xr + (c + 1) * 64;
#pragma unroll
            for (int t = 0; t < 8; ++t)
                nb[t] = *(const float4*)(xc + (t >> 1) * 16 + (t & 1) * 4);
            __builtin_amdgcn_sched_barrier(0);
        }
        // compute chunk c from the current buffer
        const float4* cb = ((c & 1) == 0) ? bufA : bufB;
#pragma unroll
        for (int kt = 0; kt < 4; ++kt) {
            float4 v0 = cb[kt * 2];
            float4 v1 = cb[kt * 2 + 1];
            int g = (c * 4 + kt) * 2;
            uint4 b0u = *(const uint4*)(bl + (size_t)g * BGRP);
            uint4 b1u = *(const uint4*)(bl + (size_t)(g + 1) * BGRP);
            union { short8 s; unsigned u[4]; } a, b0, b1;
            a.u[0] = f2bf(v0.x) | (f2bf(v0.y) << 16);
            a.u[1] = f2bf(v0.z) | (f2bf(v0.w) << 16);
            a.u[2] = f2bf(v1.x) | (f2bf(v1.y) << 16);
            a.u[3] = f2bf(v1.z) | (f2bf(v1.w) << 16);
            b0.u[0] = b0u.x; b0.u[1] = b0u.y; b0.u[2] = b0u.z; b0.u[3] = b0u.w;
            b1.u[0] = b1u.x; b1.u[1] = b1u.y; b1.u[2] = b1u.z; b1.u[3] = b1u.w;
            acc0 = __builtin_amdgcn_mfma_f32_32x32x16_bf16(a.s, b0.s, acc0, 0, 0, 0);
            acc1 = __builtin_amdgcn_mfma_f32_32x32x16_bf16(a.s, b1.s, acc1, 0, 0, 0);
        }
    }

    // ---- epilogue (wave-private): gates in-register (C/D: col=lane&31,
    // row=(reg&3)+8*(reg>>2)+4*(lane>>5)), h -> LDS, split fc head.
    float* Hw = Hs + wave * TILE * HSTR;
    const int nc = lane & 31;
    const float bzn = bz[nc];
    const float bhn = bh[nc];
#pragma unroll
    for (int r = 0; r < 16; ++r) {
        int row = (r & 3) + 8 * (r >> 2) + 4 * (lane >> 5);
        float z = fast_sigmoid(acc0[r] + bzn);
        float t = fast_tanh   (acc1[r] + bhn);
        Hw[row * HSTR + nc] = (1.0f - z) * t;
    }
    // within-wave DS ordering: drain writes before cross-lane reads
    asm volatile("s_waitcnt lgkmcnt(0)" ::: "memory");

    const int nl   = lane & 31;
    const int half = lane >> 5;
    const float* hp = Hw + nl * HSTR;
    float h[32];
#pragma unroll
    for (int q = 0; q < 8; ++q) {
        float4 v = *(const float4*)(hp + q * 4);
        h[q * 4 + 0] = v.x; h[q * 4 + 1] = v.y;
        h[q * 4 + 2] = v.z; h[q * 4 + 3] = v.w;
    }
    float part = 0.0f;
    for (int jj = 0; jj < 16; ++jj) {
        int j = (half << 4) + jj;            // 2 addrs/wave -> broadcastish
        float s = fc1b[j];
#pragma unroll
        for (int o = 0; o < 32; ++o)
            s = fmaf(h[o], fc1w[o * 32 + j], s);
        part = fmaf(fmaxf(s, 0.0f), fc2w[j], part);
    }
    part += __shfl_xor(part, 32);            // combine the two j-halves
    if (half == 0) {
        int gn = node0 + wave * TILE + nl;
        if (gn < n_nodes)
            out[gn] = fast_sigmoid(part + fc2b[0]);   // 32-lane coalesced
    }
}

extern "C" void kernel_launch(void* const* d_in, const int* in_sizes, int n_in,
                              void* d_out, int out_size, void* d_ws, size_t ws_size,
                              hipStream_t stream) {
    // 0:x 1:edge_index(dead) 2:w_z 3:b_z 4:w_r(dead) 5:b_r(dead)
    // 6:w_h 7:b_h 8:fc1_w 9:fc1_b 10:fc2_w 11:fc2_b
    const float* x    = (const float*)d_in[0];
    const float* wz   = (const float*)d_in[2];
    const float* bz   = (const float*)d_in[3];
    const float* wh   = (const float*)d_in[6];
    const float* bh   = (const float*)d_in[7];
    const float* fc1w = (const float*)d_in[8];
    const float* fc1b = (const float*)d_in[9];
    const float* fc2w = (const float*)d_in[10];
    const float* fc2b = (const float*)d_in[11];
    float* out = (float*)d_out;
    unsigned short* Wf = (unsigned short*)d_ws;   // 32 KB of B-fragments

    const int n = in_sizes[0] / NF;   // 100000

    prep_W<<<(NF * 64 + 255) / 256, 256, 0, stream>>>(wz, wh, Wf);
    rgcn_main<<<(n + MB - 1) / MB, NTHR, 0, stream>>>(
        x, Wf, bz, bh, fc1w, fc1b, fc2w, fc2b, out, n);
}